// Round 1
// baseline (690.676 us; speedup 1.0000x reference)
//
#include <hip/hip_runtime.h>

#define BATCH 32
#define NATOM 1024
#define DIM   384
#define NH1   256
#define NH2   192
#define NE    4

__global__ void zero_kernel(float* __restrict__ out) {
    int i = blockIdx.x * blockDim.x + threadIdx.x;
    if (i < BATCH) out[i] = 0.0f;
}

__global__ __launch_bounds__(256) void ani_atom_kernel(
    const float* __restrict__ rep,      // [B, A, D]
    const int*   __restrict__ species,  // [B, A]
    const float* __restrict__ W1,       // [E, D, H1]
    const float* __restrict__ b1,       // [E, H1]
    const float* __restrict__ Wh,       // [E, H1, H2]
    const float* __restrict__ bh,       // [E, H2]
    const float* __restrict__ W2,       // [E, H2]
    const float* __restrict__ b2,       // [E]
    float* __restrict__ out)            // [B]
{
    const int atom = blockIdx.x;            // 0 .. B*A-1
    const int b    = atom / NATOM;
    const int t    = threadIdx.x;
    const int e    = species[atom];

    __shared__ float xs[DIM];
    __shared__ float h1s[NH1];
    __shared__ float wsum[4];

    // stage x into LDS
    for (int i = t; i < DIM; i += 256)
        xs[i] = rep[(size_t)atom * DIM + i];
    __syncthreads();

    // ---- layer 1: h1 = x @ W1[e] + b1[e]   (NO activation — reference quirk)
    {
        const float* w = W1 + (size_t)e * DIM * NH1 + t;   // column t
        float acc = b1[e * NH1 + t];
        #pragma unroll 8
        for (int d = 0; d < DIM; ++d)
            acc = fmaf(xs[d], w[(size_t)d * NH1], acc);    // coalesced across t
        h1s[t] = acc;
    }
    __syncthreads();

    // ---- layer 2: h2 = relu(h1 @ Wh[e] + bh[e]);  energy_k = h2_k * W2[e][k]
    float energy = 0.0f;
    if (t < NH2) {
        const float* w = Wh + (size_t)e * NH1 * NH2 + t;   // column t
        float acc = bh[e * NH2 + t];
        #pragma unroll 8
        for (int h = 0; h < NH1; ++h)
            acc = fmaf(h1s[h], w[(size_t)h * NH2], acc);
        acc = fmaxf(acc, 0.0f);
        energy = acc * W2[e * NH2 + t];
    }

    // ---- block reduction (wave64 shuffle, then 4-wave LDS combine)
    for (int off = 32; off > 0; off >>= 1)
        energy += __shfl_down(energy, off, 64);
    if ((t & 63) == 0) wsum[t >> 6] = energy;
    __syncthreads();
    if (t == 0) {
        float tot = wsum[0] + wsum[1] + wsum[2] + wsum[3] + b2[e];
        atomicAdd(&out[b], tot);   // device-scope by default on CDNA
    }
}

extern "C" void kernel_launch(void* const* d_in, const int* in_sizes, int n_in,
                              void* d_out, int out_size, void* d_ws, size_t ws_size,
                              hipStream_t stream) {
    const float* rep     = (const float*)d_in[0];
    const int*   species = (const int*)  d_in[1];
    const float* W1      = (const float*)d_in[2];
    const float* b1      = (const float*)d_in[3];
    const float* Wh      = (const float*)d_in[4];
    const float* bh      = (const float*)d_in[5];
    const float* W2      = (const float*)d_in[6];
    const float* b2      = (const float*)d_in[7];
    float* out = (float*)d_out;

    zero_kernel<<<1, 64, 0, stream>>>(out);
    ani_atom_kernel<<<BATCH * NATOM, 256, 0, stream>>>(
        rep, species, W1, b1, Wh, bh, W2, b2, out);
}